// Round 8
// baseline (510.994 us; speedup 1.0000x reference)
//
#include <hip/hip_runtime.h>
#include <stdint.h>

#define B_ 2
#define N_ 4096
#define D_ 256
#define H_ 8
#define DH_ 64
#define INNER_ 512
#define NBH 16
#define PAD 72    // 144 B row stride: 16B-aligned (NEVER pad to non-multiple of 8!)
#define FPAD 80   // 80 B row stride: 16B-aligned

typedef unsigned short ushort_t;
typedef __attribute__((ext_vector_type(8))) short short8;
typedef __attribute__((ext_vector_type(4))) float float4v;
typedef __attribute__((ext_vector_type(4))) unsigned short ushort4v;
typedef __attribute__((ext_vector_type(4))) unsigned int uint4v;

__device__ __forceinline__ ushort_t f2bf(float f) {
    union { float f; unsigned int u; } v; v.f = f;
    unsigned int r = v.u + 0x7FFFu + ((v.u >> 16) & 1u);
    return (ushort_t)(r >> 16);
}
__device__ __forceinline__ float bf2f(ushort_t u) {
    union { unsigned int u; float f; } v; v.u = ((unsigned int)u) << 16;
    return v.f;
}
// full signed fp8 e4m3 encode with subnormal + clamp handling (for t values)
__device__ __forceinline__ unsigned char f2fp8s(float f) {
    union { float f; unsigned int u; } v; v.f = f;
    unsigned int s = (v.u >> 24) & 0x80u;
    v.u &= 0x7FFFFFFFu;
    float a = v.f;
    if (a >= 448.f) return (unsigned char)(s | 0x7E);
    if (a < 0.015625f) {
        int m = (int)(a * 512.f + 0.5f);
        return (unsigned char)(s | (unsigned)m);
    }
    unsigned int u = v.u + 0x7FFFFu + ((v.u >> 20) & 1u);
    return (unsigned char)(s | (((u >> 20) & 0x7FF) - 960));
}
// 2^x via v_exp_f32; s_nop covers the trans->VALU wait state.
__device__ __forceinline__ float fexp2(float x) {
    float r;
    asm volatile("v_exp_f32 %0, %1\n\ts_nop 0" : "=v"(r) : "v"(x));
    return r;
}

// ---------------- prep: bf16 conversions + weight transposes ----------------
__global__ __launch_bounds__(256) void prep_kernel(
    const float* __restrict__ x, const float* __restrict__ Wq,
    const float* __restrict__ Wk, const float* __restrict__ Wv,
    const float* __restrict__ Wo,
    ushort_t* __restrict__ xb, ushort_t* __restrict__ WqkvT,
    ushort_t* __restrict__ WoT) {
    int idx = blockIdx.x * 256 + threadIdx.x;
    const int total_x = B_ * N_ * D_;
    const int total_wqkv = 3 * INNER_ * D_;
    const int total_wo = D_ * INNER_;
    if (idx < total_x) { xb[idx] = f2bf(x[idx]); return; }
    idx -= total_x;
    if (idx < total_wqkv) {
        int n = idx >> 8, k = idx & 255;
        int which = n >> 9, nn = n & 511;
        const float* W = (which == 0) ? Wq : ((which == 1) ? Wk : Wv);
        WqkvT[idx] = f2bf(W[k * INNER_ + nn]);
        return;
    }
    idx -= total_wqkv;
    if (idx < total_wo) {
        int c = idx >> 9, k = idx & 511;
        WoT[idx] = f2bf(Wo[k * D_ + c]);
    }
}

// ---------------- fused QKV projection GEMM + per-head LayerNorm ------------
// Q is pre-scaled by 0.125*log2(e) so the poly pass can use raw v_exp_f32.
// V tiles (tileN>=8) never hit HBM as raw V: the epilogue's 16-lane row group
// holds the full 64-d head vector (d = ni*16+r), so LN reduces via 3 adds +
// shfl_xor(1,2,4,8), then writes y = c0*vln and fp8 t0T directly.
__global__ __launch_bounds__(256) void proj_gemm(
    const ushort_t* __restrict__ xb, const ushort_t* __restrict__ WqkvT,
    const float* __restrict__ gamma, const float* __restrict__ beta,
    const float* __restrict__ coeffs,
    ushort_t* __restrict__ Qb, ushort_t* __restrict__ Kb,
    unsigned char* __restrict__ t0T, float* __restrict__ y) {
    __shared__ ushort_t As[128][PAD];
    __shared__ ushort_t Bs[128][PAD];
    int bid = blockIdx.x;
    int tileN = bid % 12, tileM = bid / 12;
    int tid = threadIdx.x;
    int w = tid >> 6, lane = tid & 63, q = lane >> 4, r = lane & 15;
    int wr = (w & 1) * 64, wc = (w >> 1) * 64;
    float4v acc[4][4];
    for (int i = 0; i < 4; i++)
        for (int j = 0; j < 4; j++)
            for (int e = 0; e < 4; e++) acc[i][j][e] = 0.f;

    for (int k0 = 0; k0 < 256; k0 += 64) {
        for (int it = 0; it < 4; it++) {
            int idx = tid + it * 256;
            int row = idx >> 3, kc = (idx & 7) * 8;
            *(short8*)&As[row][kc] =
                *(const short8*)&xb[(size_t)(tileM * 128 + row) * 256 + k0 + kc];
            *(short8*)&Bs[row][kc] =
                *(const short8*)&WqkvT[(size_t)(tileN * 128 + row) * 256 + k0 + kc];
        }
        __syncthreads();
        for (int kk = 0; kk < 64; kk += 32) {
            short8 a[4], b[4];
            for (int mi = 0; mi < 4; mi++)
                a[mi] = *(const short8*)&As[wr + mi * 16 + r][kk + q * 8];
            for (int ni = 0; ni < 4; ni++)
                b[ni] = *(const short8*)&Bs[wc + ni * 16 + r][kk + q * 8];
            for (int mi = 0; mi < 4; mi++)
                for (int ni = 0; ni < 4; ni++)
                    acc[mi][ni] = __builtin_amdgcn_mfma_f32_16x16x32_bf16(
                        a[mi], b[ni], acc[mi][ni], 0, 0, 0);
        }
        __syncthreads();
    }
    if (tileN < 8) {
        // Q / K epilogue (unchanged)
        for (int mi = 0; mi < 4; mi++)
            for (int ni = 0; ni < 4; ni++)
                for (int reg = 0; reg < 4; reg++) {
                    int grow = tileM * 128 + wr + mi * 16 + q * 4 + reg;
                    int gcol = tileN * 128 + wc + ni * 16 + r;
                    float v = acc[mi][ni][reg];
                    int which = gcol >> 9, inner = gcol & 511;
                    int h = inner >> 6, d = inner & 63;
                    int b = grow >> 12, n = grow & 4095;
                    size_t off = (((size_t)(b * H_ + h)) * N_ + n) * DH_ + d;
                    if (which == 0) Qb[off] = f2bf(v * 0.18033688011112042f);
                    else Kb[off] = f2bf(v);
                }
    } else {
        // V epilogue: fused per-head LayerNorm + y init + transposed fp8 t0
        int h = (((tileN - 8) * 128) + wc) >> 6;       // wave-uniform head
        float c0 = coeffs[h * 4];
        float gm[4], bt[4];
#pragma unroll
        for (int ni = 0; ni < 4; ni++) {
            gm[ni] = gamma[ni * 16 + r];
            bt[ni] = beta[ni * 16 + r];
        }
#pragma unroll
        for (int mi = 0; mi < 4; mi++)
#pragma unroll
            for (int reg = 0; reg < 4; reg++) {
                float s = acc[mi][0][reg] + acc[mi][1][reg]
                        + acc[mi][2][reg] + acc[mi][3][reg];
                float s2 = acc[mi][0][reg] * acc[mi][0][reg]
                         + acc[mi][1][reg] * acc[mi][1][reg]
                         + acc[mi][2][reg] * acc[mi][2][reg]
                         + acc[mi][3][reg] * acc[mi][3][reg];
#pragma unroll
                for (int m = 1; m <= 8; m <<= 1) {   // reduce over r (lane bits 0-3)
                    s  += __shfl_xor(s, m, 64);
                    s2 += __shfl_xor(s2, m, 64);
                }
                float mu = s * (1.f / 64.f);
                float var = s2 * (1.f / 64.f) - mu * mu;
                float rinv = rsqrtf(var + 1e-5f);
                int grow = tileM * 128 + wr + mi * 16 + q * 4 + reg;
                int b = grow >> 12, n = grow & 4095;
                int bh = b * H_ + h;
                float* yp = y + ((size_t)bh * N_ + n) * 64;
                unsigned char* tp = t0T + (size_t)bh * 64 * N_ + n;
#pragma unroll
                for (int ni = 0; ni < 4; ni++) {
                    float vln = (acc[mi][ni][reg] - mu) * rinv * gm[ni] + bt[ni];
                    yp[ni * 16 + r] = c0 * vln;
                    tp[(size_t)(ni * 16 + r) * 4096] = f2fp8s(vln);
                }
            }
    }
}

// ---------------- fused flash-style polynomial pass (K via global) ----------
// Block = 128 output rows, 512 threads, k-split 2 (waves 0-3: [0,2048),
// waves 4-7: [2048,4096)), grid 512 = 2 blocks/CU, 16 waves/CU.
// NEW vs R7: K fragments load straight from GLOBAL into registers — the
// fragment addresses depend only on (r,q), so all 8 waves/CU load identical
// lines (L1/L2-served; K per bh = 512 KB, L2-resident under the XCD swizzle).
// This removes 2/3 of LDS traffic and the K-read bank conflicts; LDS now
// holds only the double-buffered t tile. The staging-time row permutation
// becomes an address map: lane (r,q), group g reads phys row
//   j = 32*(g>>1) + 4*(g&1) + 8*((r>>2)&3) + (r&3)
// (inverse of the old Lrow map — S values bit-identical to R7).
// g0/g1 fragments prefetch one phase ahead; g2/g3 load at phase start with
// ~300 cyc of MFB cover. WGBAR (lgkmcnt-only) keeps K loads in flight
// across barriers.

#define MFB(a, b, c) __builtin_amdgcn_mfma_f32_16x16x32_bf16(a, b, c, 0, 0, 0)
#define MFP(a, b, c) __builtin_amdgcn_mfma_f32_16x16x32_fp8_fp8(a, b, c, 0, 0, 0)

__device__ __forceinline__ long pk8(float4v x, float4v y) {
    int d0 = __builtin_amdgcn_cvt_pk_fp8_f32(fexp2(x[0]), fexp2(x[1]), 0, false);
    d0 = __builtin_amdgcn_cvt_pk_fp8_f32(fexp2(x[2]), fexp2(x[3]), d0, true);
    int d1 = __builtin_amdgcn_cvt_pk_fp8_f32(fexp2(y[0]), fexp2(y[1]), 0, false);
    d1 = __builtin_amdgcn_cvt_pk_fp8_f32(fexp2(y[2]), fexp2(y[3]), d1, true);
    return (long)(((unsigned long)(unsigned int)d1 << 32) | (unsigned int)d0);
}

#define WGBAR()                                                \
    do {                                                       \
        asm volatile("s_waitcnt lgkmcnt(0)" ::: "memory");     \
        __builtin_amdgcn_sched_barrier(0);                     \
        __builtin_amdgcn_s_barrier();                          \
        __builtin_amdgcn_sched_barrier(0);                     \
    } while (0)

// One chunk phase: compute chunk at kc with (pf* prefetched g01 + in-phase
// g23), stage t into TsNxt, prefetch next chunk's g01 into pf*.
#define POLY_PHASE(TsCur, TsNxt)                                               \
    {                                                                          \
        short8 c20 = *(const short8*)(kc + 2048);                              \
        short8 c21 = *(const short8*)(kc + 2080);                              \
        short8 c30 = *(const short8*)(kc + 2304);                              \
        short8 c31 = *(const short8*)(kc + 2336);                              \
        short8 nf00 = *(const short8*)(kc + 4096);                             \
        short8 nf01 = *(const short8*)(kc + 4128);                             \
        short8 nf10 = *(const short8*)(kc + 4352);                             \
        short8 nf11 = *(const short8*)(kc + 4384);                             \
        kc += 4096;                                                            \
        *(uint4v*)&TsNxt[half][srow][scol] = pt;                               \
        pt = *(const uint4v*)tpl;                                              \
        tpl += 64;                                                             \
        float4v s00, s01, s10, s11, s20, s21, s30, s31;                        \
        s00 = MFB(pf01, qf1, MFB(pf00, qf0, zf));                              \
        s01 = MFB(pf01, qf3, MFB(pf00, qf2, zf));                              \
        s10 = MFB(pf11, qf1, MFB(pf10, qf0, zf));                              \
        s11 = MFB(pf11, qf3, MFB(pf10, qf2, zf));                              \
        s20 = MFB(c21, qf1, MFB(c20, qf0, zf));                                \
        s21 = MFB(c21, qf3, MFB(c20, qf2, zf));                                \
        s30 = MFB(c31, qf1, MFB(c30, qf0, zf));                                \
        s31 = MFB(c31, qf3, MFB(c30, qf2, zf));                                \
        long eA0 = pk8(s00, s10), eB0 = pk8(s20, s30);                         \
        long eA1 = pk8(s01, s11), eB1 = pk8(s21, s31);                         \
        long b0 = *(const long*)&TsCur[half][r][q * 8];                        \
        long b1 = *(const long*)&TsCur[half][16 + r][q * 8];                   \
        long b2 = *(const long*)&TsCur[half][32 + r][q * 8];                   \
        long b3 = *(const long*)&TsCur[half][48 + r][q * 8];                   \
        acc0[0] = MFP(eA0, b0, acc0[0]); acc1[0] = MFP(eA1, b0, acc1[0]);      \
        acc0[1] = MFP(eA0, b1, acc0[1]); acc1[1] = MFP(eA1, b1, acc1[1]);      \
        acc0[2] = MFP(eA0, b2, acc0[2]); acc1[2] = MFP(eA1, b2, acc1[2]);      \
        acc0[3] = MFP(eA0, b3, acc0[3]); acc1[3] = MFP(eA1, b3, acc1[3]);      \
        accs0 = MFP(eA0, bones, accs0);  accs1 = MFP(eA1, bones, accs1);       \
        b0 = *(const long*)&TsCur[half][r][32 + q * 8];                        \
        b1 = *(const long*)&TsCur[half][16 + r][32 + q * 8];                   \
        b2 = *(const long*)&TsCur[half][32 + r][32 + q * 8];                   \
        b3 = *(const long*)&TsCur[half][48 + r][32 + q * 8];                   \
        acc0[0] = MFP(eB0, b0, acc0[0]); acc1[0] = MFP(eB1, b0, acc1[0]);      \
        acc0[1] = MFP(eB0, b1, acc0[1]); acc1[1] = MFP(eB1, b1, acc1[1]);      \
        acc0[2] = MFP(eB0, b2, acc0[2]); acc1[2] = MFP(eB1, b2, acc1[2]);      \
        acc0[3] = MFP(eB0, b3, acc0[3]); acc1[3] = MFP(eB1, b3, acc1[3]);      \
        accs0 = MFP(eB0, bones, accs0);  accs1 = MFP(eB1, bones, accs1);       \
        pf00 = nf00; pf01 = nf01; pf10 = nf10; pf11 = nf11;                    \
    }                                                                          \
    WGBAR();

__global__ __launch_bounds__(512, 4) void poly_pass(
    const ushort_t* __restrict__ Qb, const ushort_t* __restrict__ Kb,
    const unsigned char* __restrict__ tinT, float* __restrict__ y,
    unsigned char* __restrict__ toutT, const float* __restrict__ coeffs,
    int kidx, int write_t) {
    __shared__ char smem[50176];
    typedef unsigned char TsArr[64][FPAD];
    TsArr* Ts0 = (TsArr*)smem;             // [2][64][80] u8 = 10240
    TsArr* Ts1 = (TsArr*)(smem + 10240);   // 10240 (epilogue reuses 50176)

    int bid0 = blockIdx.x;
    // XCD-chunked swizzle: 512 blocks, 8 XCDs -> each XCD owns 2 contiguous bh
    int bid = ((bid0 & 7) << 6) | (bid0 >> 3);
    int bh = bid >> 5, ti = bid & 31;              // 32 tiles of 128 rows per bh
    const ushort_t* Q = Qb + (size_t)bh * N_ * 64;
    const ushort_t* K = Kb + (size_t)bh * N_ * 64;
    const unsigned char* tin = tinT + (size_t)bh * 64 * N_;
    int tid = threadIdx.x, w = tid >> 6, lane = tid & 63, q = lane >> 4, r = lane & 15;
    int half = w >> 2, wsub = w & 3;
    const float4v zf = {0.f, 0.f, 0.f, 0.f};

    // Q fragments for this wave's 32 rows (two 16-row i-halves), whole k-loop
    const ushort_t* qp = Q + (size_t)(ti * 128 + wsub * 32 + r) * 64 + q * 8;
    short8 qf0 = *(const short8*)qp;               // half0, d = q*8..
    short8 qf1 = *(const short8*)(qp + 32);        // half0, d = 32+q*8..
    short8 qf2 = *(const short8*)(qp + 16 * 64);   // half1
    short8 qf3 = *(const short8*)(qp + 16 * 64 + 32);

    float4v acc0[4], acc1[4], accs0, accs1;
    for (int e = 0; e < 4; e++) { accs0[e] = 0.f; accs1[e] = 0.f; }
    for (int j = 0; j < 4; j++)
        for (int e = 0; e < 4; e++) { acc0[j][e] = 0.f; acc1[j][e] = 0.f; }
    const long bones = 0x3838383838383838L;  // 8x fp8(1.0)

    // K fragment base: inverse-permuted row within each 64-chunk (g=0, h=0);
    // group offsets: g1 = +4 rows (256), g2 = +32 rows (2048), g3 = +36 (2304)
    int Drow = ((r >> 2) & 3) * 8 + (r & 3);
    const ushort_t* kc = K + (size_t)(half * 2048 + Drow) * 64 + q * 8;

    // t staging map: threads 0-255 stage half0's stream, 256-511 half1's
    int tl = tid & 255;
    int srow = tl >> 2, scol = (tl & 3) * 16;      // t: 16B/thread
    const unsigned char* tp = tin + (size_t)srow * 4096 + half * 2048 + scol;

    // prologue: stage t chunk0, t chunk1 in reg, K chunk0 g01 in regs
    {
        uint4v tv = *(const uint4v*)tp;
        *(uint4v*)&Ts0[half][srow][scol] = tv;
    }
    uint4v pt = *(const uint4v*)(tp + 64);
    const unsigned char* tpl = tp + 2 * 64;
    short8 pf00 = *(const short8*)(kc);
    short8 pf01 = *(const short8*)(kc + 32);
    short8 pf10 = *(const short8*)(kc + 256);
    short8 pf11 = *(const short8*)(kc + 288);
    WGBAR();

    for (int it = 0; it < 32; it += 2) {
        POLY_PHASE(Ts0, Ts1);      // compute chunk it,   stage t(it+1)
        POLY_PHASE(Ts1, Ts0);      // compute chunk it+1, stage t(it+2)
    }

    // ---- epilogue: LDS combine of the two k-halves, then normalize ----
    float* ULDS = (float*)smem;                              // 40960 B
    unsigned char (*TT)[144] = (unsigned char(*)[144])(smem + 40960);  // 9216 B

    if (half == 1) {
        float* ub = ULDS + (size_t)(wsub * 64 + lane) * 40;
#pragma unroll
        for (int j = 0; j < 4; j++) {
            *(float4v*)(ub + j * 4) = acc0[j];
            *(float4v*)(ub + 16 + j * 4) = acc1[j];
        }
        *(float4v*)(ub + 32) = accs0;
        *(float4v*)(ub + 36) = accs1;
    }
    WGBAR();
    if (half == 0) {
        const float* ub = ULDS + (size_t)(wsub * 64 + lane) * 40;
#pragma unroll
        for (int j = 0; j < 4; j++) {
            acc0[j] += *(const float4v*)(ub + j * 4);
            acc1[j] += *(const float4v*)(ub + 16 + j * 4);
        }
        accs0 += *(const float4v*)(ub + 32);
        accs1 += *(const float4v*)(ub + 36);

        int h = bh & 7;
        float ck = coeffs[h * 4 + kidx];
        float rinv0[4], rinv1[4];
#pragma unroll
        for (int reg = 0; reg < 4; reg++) {
            rinv0[reg] = 1.f / accs0[reg];
            rinv1[reg] = 1.f / accs1[reg];
        }
        float tv0[4][4], tv1[4][4];
#pragma unroll
        for (int ni = 0; ni < 4; ni++)
#pragma unroll
            for (int reg = 0; reg < 4; reg++) {
                tv0[ni][reg] = acc0[ni][reg] * rinv0[reg];
                tv1[ni][reg] = acc1[ni][reg] * rinv1[reg];
            }
#pragma unroll
        for (int reg = 0; reg < 4; reg++) {
            int il = wsub * 32 + q * 4 + reg;
            float* yp0 = y + ((size_t)bh * N_ + (size_t)ti * 128 + il) * 64;
            float* yp1 = yp0 + 16 * 64;
#pragma unroll
            for (int ni = 0; ni < 4; ni++) {
                yp0[ni * 16 + r] += ck * tv0[ni][reg];
                yp1[ni * 16 + r] += ck * tv1[ni][reg];
            }
        }
        if (write_t) {
#pragma unroll
            for (int ni = 0; ni < 4; ni++) {
                int p0 = __builtin_amdgcn_cvt_pk_fp8_f32(tv0[ni][0], tv0[ni][1], 0, false);
                p0 = __builtin_amdgcn_cvt_pk_fp8_f32(tv0[ni][2], tv0[ni][3], p0, true);
                *(unsigned int*)&TT[ni * 16 + r][wsub * 32 + q * 4] = (unsigned int)p0;
                int p1 = __builtin_amdgcn_cvt_pk_fp8_f32(tv1[ni][0], tv1[ni][1], 0, false);
                p1 = __builtin_amdgcn_cvt_pk_fp8_f32(tv1[ni][2], tv1[ni][3], p1, true);
                *(unsigned int*)&TT[ni * 16 + r][wsub * 32 + 16 + q * 4] = (unsigned int)p1;
            }
        }
    }
    if (write_t) {
        WGBAR();
        int drow = tid >> 3, dcol = (tid & 7) * 16;   // 64 rows x 128 cols
        uint4v vv = *(const uint4v*)&TT[drow][dcol];
        *(uint4v*)&toutT[(size_t)bh * 64 * N_ + (size_t)drow * N_ + ti * 128 + dcol] = vv;
    }
}

// ---------------- output projection: merged[8192,512] x Wo[512,256] ---------
__global__ __launch_bounds__(256) void out_gemm(
    const float* __restrict__ y, const ushort_t* __restrict__ WoT,
    float* __restrict__ out) {
    __shared__ ushort_t As[128][PAD];
    __shared__ ushort_t Bs[64][PAD];
    int bid = blockIdx.x;
    int tileN = bid & 3, tileM = bid >> 2;
    int tid = threadIdx.x, w = tid >> 6, lane = tid & 63, q = lane >> 4, r = lane & 15;
    int wr = w * 32;
    float4v acc[2][4];
    for (int i = 0; i < 2; i++)
        for (int j = 0; j < 4; j++)
            for (int e = 0; e < 4; e++) acc[i][j][e] = 0.f;

    for (int k0 = 0; k0 < 512; k0 += 64) {
        int h = k0 >> 6;
        for (int it = 0; it < 8; it++) {
            int idx = tid + it * 256;
            int row = idx >> 4, kc = (idx & 15) * 4;
            int grow = tileM * 128 + row;
            int b = grow >> 12, n = grow & 4095;
            const float4* src =
                (const float4*)&y[(((size_t)(b * H_ + h)) * N_ + n) * 64 + kc];
            float4 v = *src;
            ushort4v pv;
            pv[0] = f2bf(v.x); pv[1] = f2bf(v.y); pv[2] = f2bf(v.z); pv[3] = f2bf(v.w);
            *(ushort4v*)&As[row][kc] = pv;
        }
        for (int it = 0; it < 2; it++) {
            int idx = tid + it * 256;
            int row = idx >> 3, kc = (idx & 7) * 8;
            *(short8*)&Bs[row][kc] =
                *(const short8*)&WoT[(size_t)(tileN * 64 + row) * 512 + k0 + kc];
        }
        __syncthreads();
        for (int kk = 0; kk < 64; kk += 32) {
            short8 a[2], b[4];
            a[0] = *(const short8*)&As[wr + r][kk + q * 8];
            a[1] = *(const short8*)&As[wr + 16 + r][kk + q * 8];
            for (int ni = 0; ni < 4; ni++)
                b[ni] = *(const short8*)&Bs[ni * 16 + r][kk + q * 8];
            for (int mi = 0; mi < 2; mi++)
                for (int ni = 0; ni < 4; ni++)
                    acc[mi][ni] = __builtin_amdgcn_mfma_f32_16x16x32_bf16(
                        a[mi], b[ni], acc[mi][ni], 0, 0, 0);
        }
        __syncthreads();
    }
    for (int mi = 0; mi < 2; mi++)
        for (int reg = 0; reg < 4; reg++) {
            int grow = tileM * 128 + wr + mi * 16 + q * 4 + reg;
            for (int ni = 0; ni < 4; ni++) {
                int gcol = tileN * 64 + ni * 16 + r;
                out[(size_t)grow * 256 + gcol] = acc[mi][ni][reg];
            }
        }
}

// ---------------------------------------------------------------------------
extern "C" void kernel_launch(void* const* d_in, const int* in_sizes, int n_in,
                              void* d_out, int out_size, void* d_ws, size_t ws_size,
                              hipStream_t stream) {
    const float* x      = (const float*)d_in[0];
    const float* Wq     = (const float*)d_in[1];
    const float* Wk     = (const float*)d_in[2];
    const float* Wv     = (const float*)d_in[3];
    const float* Wo     = (const float*)d_in[4];
    const float* gamma  = (const float*)d_in[5];
    const float* beta   = (const float*)d_in[6];
    const float* coeffs = (const float*)d_in[7];
    float* out = (float*)d_out;

    char* ws = (char*)d_ws;
    size_t off = 0;
    auto alloc = [&](size_t bytes) -> void* {
        void* p = ws + off;
        off += (bytes + 255) & ~(size_t)255;
        return p;
    };
    ushort_t* xb    = (ushort_t*)alloc((size_t)B_ * N_ * D_ * 2);
    ushort_t* WqkvT = (ushort_t*)alloc((size_t)3 * INNER_ * D_ * 2);
    ushort_t* WoT   = (ushort_t*)alloc((size_t)D_ * INNER_ * 2);
    ushort_t* Qb    = (ushort_t*)alloc((size_t)NBH * N_ * DH_ * 2);
    ushort_t* Kb    = (ushort_t*)alloc((size_t)NBH * N_ * DH_ * 2);
    unsigned char* t0T = (unsigned char*)alloc((size_t)NBH * DH_ * N_);
    unsigned char* t1T = (unsigned char*)alloc((size_t)NBH * DH_ * N_);
    float*    y     = (float*)alloc((size_t)NBH * N_ * DH_ * 4);

    const int prep_total = B_ * N_ * D_ + 3 * INNER_ * D_ + D_ * INNER_;
    prep_kernel<<<(prep_total + 255) / 256, 256, 0, stream>>>(
        x, Wq, Wk, Wv, Wo, xb, WqkvT, WoT);
    proj_gemm<<<768, 256, 0, stream>>>(xb, WqkvT, gamma, beta, coeffs,
                                       Qb, Kb, t0T, y);

    poly_pass<<<NBH * 32, 512, 0, stream>>>(Qb, Kb, t0T, y, t1T, coeffs, 1, 1);
    poly_pass<<<NBH * 32, 512, 0, stream>>>(Qb, Kb, t1T, y, t0T, coeffs, 2, 1);
    poly_pass<<<NBH * 32, 512, 0, stream>>>(Qb, Kb, t0T, y, t1T, coeffs, 3, 0);

    out_gemm<<<256, 256, 0, stream>>>(y, WoT, out);
}

// Round 9
// 316.031 us; speedup vs baseline: 1.6169x; 1.6169x over previous
//
#include <hip/hip_runtime.h>
#include <stdint.h>

#define B_ 2
#define N_ 4096
#define D_ 256
#define H_ 8
#define DH_ 64
#define INNER_ 512
#define NBH 16
#define PAD 72    // 144 B row stride: 16B-aligned (NEVER pad to non-multiple of 8!)
#define FPAD 80   // 80 B row stride: 16B-aligned

typedef unsigned short ushort_t;
typedef __attribute__((ext_vector_type(8))) short short8;
typedef __attribute__((ext_vector_type(4))) float float4v;
typedef __attribute__((ext_vector_type(4))) unsigned short ushort4v;
typedef __attribute__((ext_vector_type(4))) unsigned int uint4v;

__device__ __forceinline__ ushort_t f2bf(float f) {
    union { float f; unsigned int u; } v; v.f = f;
    unsigned int r = v.u + 0x7FFFu + ((v.u >> 16) & 1u);
    return (ushort_t)(r >> 16);
}
__device__ __forceinline__ float bf2f(ushort_t u) {
    union { unsigned int u; float f; } v; v.u = ((unsigned int)u) << 16;
    return v.f;
}
// full signed fp8 e4m3 encode with subnormal + clamp handling
__device__ __forceinline__ unsigned char f2fp8s(float f) {
    union { float f; unsigned int u; } v; v.f = f;
    unsigned int s = (v.u >> 24) & 0x80u;
    v.u &= 0x7FFFFFFFu;
    float a = v.f;
    if (a >= 448.f) return (unsigned char)(s | 0x7E);
    if (a < 0.015625f) {
        int m = (int)(a * 512.f + 0.5f);
        return (unsigned char)(s | (unsigned)m);
    }
    unsigned int u = v.u + 0x7FFFFu + ((v.u >> 20) & 1u);
    return (unsigned char)(s | (((u >> 20) & 0x7FF) - 960));
}
// 2^x via v_exp_f32; s_nop covers the trans->VALU wait state.
__device__ __forceinline__ float fexp2(float x) {
    float r;
    asm volatile("v_exp_f32 %0, %1\n\ts_nop 0" : "=v"(r) : "v"(x));
    return r;
}

// ---------------- prep: bf16 conversions + weight transposes ----------------
__global__ __launch_bounds__(256) void prep_kernel(
    const float* __restrict__ x, const float* __restrict__ Wq,
    const float* __restrict__ Wk, const float* __restrict__ Wv,
    const float* __restrict__ Wo,
    ushort_t* __restrict__ xb, ushort_t* __restrict__ WqkvT,
    ushort_t* __restrict__ WoT) {
    int idx = blockIdx.x * 256 + threadIdx.x;
    const int total_x = B_ * N_ * D_;
    const int total_wqkv = 3 * INNER_ * D_;
    const int total_wo = D_ * INNER_;
    if (idx < total_x) { xb[idx] = f2bf(x[idx]); return; }
    idx -= total_x;
    if (idx < total_wqkv) {
        int n = idx >> 8, k = idx & 255;
        int which = n >> 9, nn = n & 511;
        const float* W = (which == 0) ? Wq : ((which == 1) ? Wk : Wv);
        WqkvT[idx] = f2bf(W[k * INNER_ + nn]);
        return;
    }
    idx -= total_wqkv;
    if (idx < total_wo) {
        int c = idx >> 9, k = idx & 511;
        WoT[idx] = f2bf(Wo[k * D_ + c]);
    }
}

// ---------------- fused QKV projection GEMM + per-head LayerNorm ------------
// Q is pre-scaled by 0.125*log2(e) so the poly pass can use raw v_exp_f32.
// V tiles (tileN>=8): LN reduces in-register (shfl over r bits), writes
// y = c0*vln directly, and emits fp8 t0^T via an LDS TRANSPOSE bounce so the
// transposed store is dwordx4-coalesced (was: 64 byte-stores/lane at
// stride-4096 — the dominant cost of this kernel in R7).
__global__ __launch_bounds__(256) void proj_gemm(
    const ushort_t* __restrict__ xb, const ushort_t* __restrict__ WqkvT,
    const float* __restrict__ gamma, const float* __restrict__ beta,
    const float* __restrict__ coeffs,
    ushort_t* __restrict__ Qb, ushort_t* __restrict__ Kb,
    unsigned char* __restrict__ t0T, float* __restrict__ y) {
    __shared__ ushort_t As[128][PAD];
    __shared__ ushort_t Bs[128][PAD];
    int bid = blockIdx.x;
    int tileN = bid % 12, tileM = bid / 12;
    int tid = threadIdx.x;
    int w = tid >> 6, lane = tid & 63, q = lane >> 4, r = lane & 15;
    int wr = (w & 1) * 64, wc = (w >> 1) * 64;
    float4v acc[4][4];
    for (int i = 0; i < 4; i++)
        for (int j = 0; j < 4; j++)
            for (int e = 0; e < 4; e++) acc[i][j][e] = 0.f;

    for (int k0 = 0; k0 < 256; k0 += 64) {
        for (int it = 0; it < 4; it++) {
            int idx = tid + it * 256;
            int row = idx >> 3, kc = (idx & 7) * 8;
            *(short8*)&As[row][kc] =
                *(const short8*)&xb[(size_t)(tileM * 128 + row) * 256 + k0 + kc];
            *(short8*)&Bs[row][kc] =
                *(const short8*)&WqkvT[(size_t)(tileN * 128 + row) * 256 + k0 + kc];
        }
        __syncthreads();
        for (int kk = 0; kk < 64; kk += 32) {
            short8 a[4], b[4];
            for (int mi = 0; mi < 4; mi++)
                a[mi] = *(const short8*)&As[wr + mi * 16 + r][kk + q * 8];
            for (int ni = 0; ni < 4; ni++)
                b[ni] = *(const short8*)&Bs[wc + ni * 16 + r][kk + q * 8];
            for (int mi = 0; mi < 4; mi++)
                for (int ni = 0; ni < 4; ni++)
                    acc[mi][ni] = __builtin_amdgcn_mfma_f32_16x16x32_bf16(
                        a[mi], b[ni], acc[mi][ni], 0, 0, 0);
        }
        __syncthreads();
    }
    if (tileN < 8) {
        // Q / K epilogue (unchanged)
        for (int mi = 0; mi < 4; mi++)
            for (int ni = 0; ni < 4; ni++)
                for (int reg = 0; reg < 4; reg++) {
                    int grow = tileM * 128 + wr + mi * 16 + q * 4 + reg;
                    int gcol = tileN * 128 + wc + ni * 16 + r;
                    float v = acc[mi][ni][reg];
                    int which = gcol >> 9, inner = gcol & 511;
                    int h = inner >> 6, d = inner & 63;
                    int b = grow >> 12, n = grow & 4095;
                    size_t off = (((size_t)(b * H_ + h)) * N_ + n) * DH_ + d;
                    if (which == 0) Qb[off] = f2bf(v * 0.18033688011112042f);
                    else Kb[off] = f2bf(v);
                }
    } else {
        // V epilogue: fused per-head LayerNorm + y init + LDS-transposed t0
        int h = (((tileN - 8) * 128) + wc) >> 6;       // wave-uniform head
        float c0 = coeffs[h * 4];
        float gm[4], bt[4];
#pragma unroll
        for (int ni = 0; ni < 4; ni++) {
            gm[ni] = gamma[ni * 16 + r];
            bt[ni] = beta[ni * 16 + r];
        }
        unsigned char (*TT)[136] = (unsigned char(*)[136])&As[0][0];  // 128x136
#pragma unroll
        for (int mi = 0; mi < 4; mi++) {
            float mu_[4], ri_[4];
#pragma unroll
            for (int reg = 0; reg < 4; reg++) {
                float s = acc[mi][0][reg] + acc[mi][1][reg]
                        + acc[mi][2][reg] + acc[mi][3][reg];
                float s2 = acc[mi][0][reg] * acc[mi][0][reg]
                         + acc[mi][1][reg] * acc[mi][1][reg]
                         + acc[mi][2][reg] * acc[mi][2][reg]
                         + acc[mi][3][reg] * acc[mi][3][reg];
#pragma unroll
                for (int m = 1; m <= 8; m <<= 1) {   // reduce over r (d-dim)
                    s  += __shfl_xor(s, m, 64);
                    s2 += __shfl_xor(s2, m, 64);
                }
                float mu = s * (1.f / 64.f);
                float var = s2 * (1.f / 64.f) - mu * mu;
                mu_[reg] = mu;
                ri_[reg] = rsqrtf(var + 1e-5f);
            }
#pragma unroll
            for (int ni = 0; ni < 4; ni++) {
                float v0 = (acc[mi][ni][0] - mu_[0]) * ri_[0] * gm[ni] + bt[ni];
                float v1 = (acc[mi][ni][1] - mu_[1]) * ri_[1] * gm[ni] + bt[ni];
                float v2 = (acc[mi][ni][2] - mu_[2]) * ri_[2] * gm[ni] + bt[ni];
                float v3 = (acc[mi][ni][3] - mu_[3]) * ri_[3] * gm[ni] + bt[ni];
                // y writes (rows n = ...+q*4+reg, cols d = ni*16+r)
                int grow0 = tileM * 128 + wr + mi * 16 + q * 4;
                int b = grow0 >> 12, n0 = grow0 & 4095;
                float* yp = y + (((size_t)(b * H_ + h)) * N_ + n0) * 64 + ni * 16 + r;
                yp[0 * 64] = c0 * v0;
                yp[1 * 64] = c0 * v1;
                yp[2 * 64] = c0 * v2;
                yp[3 * 64] = c0 * v3;
                // fp8 pack along n (reg direction) -> transpose tile
                int p = __builtin_amdgcn_cvt_pk_fp8_f32(v0, v1, 0, false);
                p = __builtin_amdgcn_cvt_pk_fp8_f32(v2, v3, p, true);
                *(unsigned int*)&TT[(wc >> 6) * 64 + ni * 16 + r]
                                   [wr + mi * 16 + q * 4] = (unsigned int)p;
            }
        }
        __syncthreads();
        // coalesced copy-out: TT[128 d-rows][128 n-cols] -> t0T[bh][d][n]
        int trow = tid >> 1, tcol = (tid & 1) * 64;
        int hh = (tileN - 8) * 2 + (trow >> 6);
        int d = trow & 63;
        int b = tileM >> 5;
        int nbase = (tileM & 31) * 128;
        unsigned char* dst = t0T + ((size_t)(b * H_ + hh) * 64 + d) * 4096 + nbase + tcol;
        const unsigned char* srcp = &TT[trow][tcol];
        *(uint4v*)(dst)      = *(const uint4v*)(srcp);
        *(uint4v*)(dst + 16) = *(const uint4v*)(srcp + 16);
        *(uint4v*)(dst + 32) = *(const uint4v*)(srcp + 32);
        *(uint4v*)(dst + 48) = *(const uint4v*)(srcp + 48);
    }
}

// ---------------- fused flash-style polynomial pass (8-wave k-split) --------
// R7-proven configuration (81.7 us/pass): block = 128 output rows, 512
// threads, waves 0-3 sweep k in [0,2048), waves 4-7 sweep [2048,4096) in an
// independent LDS stream -> 16 waves/CU, 2 blocks/CU (barrier-decorrelated).
// Partial (u, rowsum) combined in LDS at the epilogue. E never touches HBM.
// K rows permuted at staging (phys j -> Lrow) so swapped-QK output packs
// straight into fp8 A-fragments. LDS strides 144 B / 80 B: 16B-aligned.

#define MFB(a, b, c) __builtin_amdgcn_mfma_f32_16x16x32_bf16(a, b, c, 0, 0, 0)
#define MFP(a, b, c) __builtin_amdgcn_mfma_f32_16x16x32_fp8_fp8(a, b, c, 0, 0, 0)

__device__ __forceinline__ long pk8(float4v x, float4v y) {
    int d0 = __builtin_amdgcn_cvt_pk_fp8_f32(fexp2(x[0]), fexp2(x[1]), 0, false);
    d0 = __builtin_amdgcn_cvt_pk_fp8_f32(fexp2(x[2]), fexp2(x[3]), d0, true);
    int d1 = __builtin_amdgcn_cvt_pk_fp8_f32(fexp2(y[0]), fexp2(y[1]), 0, false);
    d1 = __builtin_amdgcn_cvt_pk_fp8_f32(fexp2(y[2]), fexp2(y[3]), d1, true);
    return (long)(((unsigned long)(unsigned int)d1 << 32) | (unsigned int)d0);
}

#define WGBAR()                                                \
    do {                                                       \
        asm volatile("s_waitcnt lgkmcnt(0)" ::: "memory");     \
        __builtin_amdgcn_sched_barrier(0);                     \
        __builtin_amdgcn_s_barrier();                          \
        __builtin_amdgcn_sched_barrier(0);                     \
    } while (0)

#define COMPUTE32(KsX, TsX)                                                     \
    {                                                                           \
        short8 a0, a1;                                                          \
        float4v s00, s10, s20, s30, s01, s11, s21, s31;                         \
        a0 = *(const short8*)&KsX[r][q * 8];                                    \
        a1 = *(const short8*)&KsX[r][32 + q * 8];                               \
        s00 = MFB(a1, qf1, MFB(a0, qf0, zf));                                   \
        s01 = MFB(a1, qf3, MFB(a0, qf2, zf));                                   \
        a0 = *(const short8*)&KsX[16 + r][q * 8];                               \
        a1 = *(const short8*)&KsX[16 + r][32 + q * 8];                          \
        s10 = MFB(a1, qf1, MFB(a0, qf0, zf));                                   \
        s11 = MFB(a1, qf3, MFB(a0, qf2, zf));                                   \
        a0 = *(const short8*)&KsX[32 + r][q * 8];                               \
        a1 = *(const short8*)&KsX[32 + r][32 + q * 8];                          \
        s20 = MFB(a1, qf1, MFB(a0, qf0, zf));                                   \
        s21 = MFB(a1, qf3, MFB(a0, qf2, zf));                                   \
        a0 = *(const short8*)&KsX[48 + r][q * 8];                               \
        a1 = *(const short8*)&KsX[48 + r][32 + q * 8];                          \
        s30 = MFB(a1, qf1, MFB(a0, qf0, zf));                                   \
        s31 = MFB(a1, qf3, MFB(a0, qf2, zf));                                   \
        long eA0 = pk8(s00, s10), eB0 = pk8(s20, s30);                          \
        long eA1 = pk8(s01, s11), eB1 = pk8(s21, s31);                          \
        long b0 = *(const long*)&TsX[r][q * 8];                                 \
        long b1 = *(const long*)&TsX[16 + r][q * 8];                            \
        long b2 = *(const long*)&TsX[32 + r][q * 8];                            \
        long b3 = *(const long*)&TsX[48 + r][q * 8];                            \
        acc0[0] = MFP(eA0, b0, acc0[0]); acc1[0] = MFP(eA1, b0, acc1[0]);       \
        acc0[1] = MFP(eA0, b1, acc0[1]); acc1[1] = MFP(eA1, b1, acc1[1]);       \
        acc0[2] = MFP(eA0, b2, acc0[2]); acc1[2] = MFP(eA1, b2, acc1[2]);       \
        acc0[3] = MFP(eA0, b3, acc0[3]); acc1[3] = MFP(eA1, b3, acc1[3]);       \
        accs0 = MFP(eA0, bones, accs0);  accs1 = MFP(eA1, bones, accs1);        \
        b0 = *(const long*)&TsX[r][32 + q * 8];                                 \
        b1 = *(const long*)&TsX[16 + r][32 + q * 8];                            \
        b2 = *(const long*)&TsX[32 + r][32 + q * 8];                            \
        b3 = *(const long*)&TsX[48 + r][32 + q * 8];                            \
        acc0[0] = MFP(eB0, b0, acc0[0]); acc1[0] = MFP(eB1, b0, acc1[0]);       \
        acc0[1] = MFP(eB0, b1, acc0[1]); acc1[1] = MFP(eB1, b1, acc1[1]);       \
        acc0[2] = MFP(eB0, b2, acc0[2]); acc1[2] = MFP(eB1, b2, acc1[2]);       \
        acc0[3] = MFP(eB0, b3, acc0[3]); acc1[3] = MFP(eB1, b3, acc1[3]);       \
        accs0 = MFP(eB0, bones, accs0);  accs1 = MFP(eB1, bones, accs1);        \
    }

__global__ __launch_bounds__(512, 4) void poly_pass(
    const ushort_t* __restrict__ Qb, const ushort_t* __restrict__ Kb,
    const unsigned char* __restrict__ tinT, float* __restrict__ y,
    unsigned char* __restrict__ toutT, const float* __restrict__ coeffs,
    int kidx, int write_t) {
    __shared__ char smem[57344];
    typedef ushort_t KsArr[64][PAD];
    typedef unsigned char TsArr[64][FPAD];
    KsArr* Ks0 = (KsArr*)smem;                     // [2][64][72] bf16 = 18432
    KsArr* Ks1 = (KsArr*)(smem + 18432);           // [2][64][72] bf16 = 18432
    TsArr* Ts0 = (TsArr*)(smem + 36864);           // [2][64][80] u8   = 10240
    TsArr* Ts1 = (TsArr*)(smem + 47104);           // [2][64][80] u8   = 10240

    int bid0 = blockIdx.x;
    // XCD-chunked swizzle: 512 blocks, 8 XCDs -> each XCD owns 2 contiguous bh
    int bid = ((bid0 & 7) << 6) | (bid0 >> 3);
    int bh = bid >> 5, ti = bid & 31;              // 32 tiles of 128 rows per bh
    const ushort_t* Q = Qb + (size_t)bh * N_ * 64;
    const ushort_t* K = Kb + (size_t)bh * N_ * 64;
    const unsigned char* tin = tinT + (size_t)bh * 64 * N_;
    int tid = threadIdx.x, w = tid >> 6, lane = tid & 63, q = lane >> 4, r = lane & 15;
    int half = w >> 2, wsub = w & 3;
    const float4v zf = {0.f, 0.f, 0.f, 0.f};

    // Q fragments for this wave's 32 rows (two 16-row i-halves), whole k-loop
    const ushort_t* qp = Q + (size_t)(ti * 128 + wsub * 32 + r) * 64 + q * 8;
    short8 qf0 = *(const short8*)qp;               // half0, d = q*8..
    short8 qf1 = *(const short8*)(qp + 32);        // half0, d = 32+q*8..
    short8 qf2 = *(const short8*)(qp + 16 * 64);   // half1
    short8 qf3 = *(const short8*)(qp + 16 * 64 + 32);

    float4v acc0[4], acc1[4], accs0, accs1;
    for (int e = 0; e < 4; e++) { accs0[e] = 0.f; accs1[e] = 0.f; }
    for (int j = 0; j < 4; j++)
        for (int e = 0; e < 4; e++) { acc0[j][e] = 0.f; acc1[j][e] = 0.f; }
    const long bones = 0x3838383838383838L;  // 8x fp8(1.0)

    // staging maps: threads 0-255 stage half0's stream, 256-511 half1's
    int tl = tid & 255;
    int krow = tl >> 2, kpart = (tl & 3) * 16;            // K: 32B/thread
    int Lrow = (krow & 32) + ((krow & 4) << 2) + (krow & 3) + ((krow >> 3) & 3) * 4;
    const ushort_t* kp = K + (size_t)(half * 2048 + krow) * 64 + kpart;
    int srow = tl >> 2, scol = (tl & 3) * 16;             // t: 16B/thread
    const unsigned char* tp = tin + (size_t)srow * 4096 + half * 2048 + scol;

    // prologue: stage chunk0, hold chunk1 in regs, running load pointers at 2
    {
        uint4v ka = *(const uint4v*)kp;
        uint4v kb = *(const uint4v*)(kp + 8);
        uint4v tv = *(const uint4v*)tp;
        *(uint4v*)&Ks0[half][Lrow][kpart] = ka;
        *(uint4v*)&Ks0[half][Lrow][kpart + 8] = kb;
        *(uint4v*)&Ts0[half][srow][scol] = tv;
    }
    uint4v pka = *(const uint4v*)(kp + 4096);
    uint4v pkb = *(const uint4v*)(kp + 4096 + 8);
    uint4v pt  = *(const uint4v*)(tp + 64);
    const ushort_t* kpl = kp + 2 * 4096;
    const unsigned char* tpl = tp + 2 * 64;
    WGBAR();

    for (int it = 0; it < 32; it += 2) {
        // phase A: compute chunk it (buf0); stage buf1 <- chunk it+1; load it+2
        *(uint4v*)&Ks1[half][Lrow][kpart] = pka;
        *(uint4v*)&Ks1[half][Lrow][kpart + 8] = pkb;
        *(uint4v*)&Ts1[half][srow][scol] = pt;
        pka = *(const uint4v*)kpl;
        pkb = *(const uint4v*)(kpl + 8);
        pt  = *(const uint4v*)tpl;
        kpl += 4096; tpl += 64;
        COMPUTE32(Ks0[half], Ts0[half]);
        WGBAR();
        // phase B: compute chunk it+1 (buf1); stage buf0 <- chunk it+2; load it+3
        *(uint4v*)&Ks0[half][Lrow][kpart] = pka;
        *(uint4v*)&Ks0[half][Lrow][kpart + 8] = pkb;
        *(uint4v*)&Ts0[half][srow][scol] = pt;
        pka = *(const uint4v*)kpl;
        pkb = *(const uint4v*)(kpl + 8);
        pt  = *(const uint4v*)tpl;
        kpl += 4096; tpl += 64;
        COMPUTE32(Ks1[half], Ts1[half]);
        WGBAR();
    }

    // ---- epilogue: LDS combine of the two k-halves, then normalize ----
    float* ULDS = (float*)smem;                              // 40960 B
    unsigned char (*TT)[144] = (unsigned char(*)[144])(smem + 40960);  // 9216 B

    if (half == 1) {
        float* ub = ULDS + (size_t)(wsub * 64 + lane) * 40;
#pragma unroll
        for (int j = 0; j < 4; j++) {
            *(float4v*)(ub + j * 4) = acc0[j];
            *(float4v*)(ub + 16 + j * 4) = acc1[j];
        }
        *(float4v*)(ub + 32) = accs0;
        *(float4v*)(ub + 36) = accs1;
    }
    WGBAR();
    if (half == 0) {
        const float* ub = ULDS + (size_t)(wsub * 64 + lane) * 40;
#pragma unroll
        for (int j = 0; j < 4; j++) {
            acc0[j] += *(const float4v*)(ub + j * 4);
            acc1[j] += *(const float4v*)(ub + 16 + j * 4);
        }
        accs0 += *(const float4v*)(ub + 32);
        accs1 += *(const float4v*)(ub + 36);

        int h = bh & 7;
        float ck = coeffs[h * 4 + kidx];
        float rinv0[4], rinv1[4];
#pragma unroll
        for (int reg = 0; reg < 4; reg++) {
            rinv0[reg] = 1.f / accs0[reg];
            rinv1[reg] = 1.f / accs1[reg];
        }
        float tv0[4][4], tv1[4][4];
#pragma unroll
        for (int ni = 0; ni < 4; ni++)
#pragma unroll
            for (int reg = 0; reg < 4; reg++) {
                tv0[ni][reg] = acc0[ni][reg] * rinv0[reg];
                tv1[ni][reg] = acc1[ni][reg] * rinv1[reg];
            }
#pragma unroll
        for (int reg = 0; reg < 4; reg++) {
            int il = wsub * 32 + q * 4 + reg;
            float* yp0 = y + ((size_t)bh * N_ + (size_t)ti * 128 + il) * 64;
            float* yp1 = yp0 + 16 * 64;
#pragma unroll
            for (int ni = 0; ni < 4; ni++) {
                yp0[ni * 16 + r] += ck * tv0[ni][reg];
                yp1[ni * 16 + r] += ck * tv1[ni][reg];
            }
        }
        if (write_t) {
#pragma unroll
            for (int ni = 0; ni < 4; ni++) {
                int p0 = __builtin_amdgcn_cvt_pk_fp8_f32(tv0[ni][0], tv0[ni][1], 0, false);
                p0 = __builtin_amdgcn_cvt_pk_fp8_f32(tv0[ni][2], tv0[ni][3], p0, true);
                *(unsigned int*)&TT[ni * 16 + r][wsub * 32 + q * 4] = (unsigned int)p0;
                int p1 = __builtin_amdgcn_cvt_pk_fp8_f32(tv1[ni][0], tv1[ni][1], 0, false);
                p1 = __builtin_amdgcn_cvt_pk_fp8_f32(tv1[ni][2], tv1[ni][3], p1, true);
                *(unsigned int*)&TT[ni * 16 + r][wsub * 32 + 16 + q * 4] = (unsigned int)p1;
            }
        }
    }
    if (write_t) {
        WGBAR();
        int drow = tid >> 3, dcol = (tid & 7) * 16;   // 64 rows x 128 cols
        uint4v vv = *(const uint4v*)&TT[drow][dcol];
        *(uint4v*)&toutT[(size_t)bh * 64 * N_ + (size_t)drow * N_ + ti * 128 + dcol] = vv;
    }
}

// ---------------- output projection: merged[8192,512] x Wo[512,256] ---------
// tileM split 128 -> 64 rows: grid 512 (2 blocks/CU) — was grid-starved at 256.
__global__ __launch_bounds__(256) void out_gemm(
    const float* __restrict__ y, const ushort_t* __restrict__ WoT,
    float* __restrict__ out) {
    __shared__ ushort_t As[64][PAD];
    __shared__ ushort_t Bs[64][PAD];
    int bid = blockIdx.x;
    int tileN = bid & 3, tileM = bid >> 2;         // tileM in [0,128)
    int tid = threadIdx.x, w = tid >> 6, lane = tid & 63, q = lane >> 4, r = lane & 15;
    int wr = w * 16;
    float4v acc[4];
    for (int j = 0; j < 4; j++)
        for (int e = 0; e < 4; e++) acc[j][e] = 0.f;

    for (int k0 = 0; k0 < 512; k0 += 64) {
        int h = k0 >> 6;
        for (int it = 0; it < 4; it++) {
            int idx = tid + it * 256;              // 0..1023
            int row = idx >> 4, kc = (idx & 15) * 4;
            int grow = tileM * 64 + row;
            int b = grow >> 12, n = grow & 4095;
            const float4* src =
                (const float4*)&y[(((size_t)(b * H_ + h)) * N_ + n) * 64 + kc];
            float4 v = *src;
            ushort4v pv;
            pv[0] = f2bf(v.x); pv[1] = f2bf(v.y); pv[2] = f2bf(v.z); pv[3] = f2bf(v.w);
            *(ushort4v*)&As[row][kc] = pv;
        }
        for (int it = 0; it < 2; it++) {
            int idx = tid + it * 256;
            int row = idx >> 3, kc = (idx & 7) * 8;
            *(short8*)&Bs[row][kc] =
                *(const short8*)&WoT[(size_t)(tileN * 64 + row) * 512 + k0 + kc];
        }
        __syncthreads();
        for (int kk = 0; kk < 64; kk += 32) {
            short8 a0, b[4];
            a0 = *(const short8*)&As[wr + r][kk + q * 8];
            for (int ni = 0; ni < 4; ni++)
                b[ni] = *(const short8*)&Bs[ni * 16 + r][kk + q * 8];
            for (int ni = 0; ni < 4; ni++)
                acc[ni] = __builtin_amdgcn_mfma_f32_16x16x32_bf16(
                    a0, b[ni], acc[ni], 0, 0, 0);
        }
        __syncthreads();
    }
    for (int reg = 0; reg < 4; reg++) {
        int grow = tileM * 64 + wr + q * 4 + reg;
        for (int ni = 0; ni < 4; ni++) {
            int gcol = tileN * 64 + ni * 16 + r;
            out[(size_t)grow * 256 + gcol] = acc[ni][reg];
        }
    }
}

// ---------------------------------------------------------------------------
extern "C" void kernel_launch(void* const* d_in, const int* in_sizes, int n_in,
                              void* d_out, int out_size, void* d_ws, size_t ws_size,
                              hipStream_t stream) {
    const float* x      = (const float*)d_in[0];
    const float* Wq     = (const float*)d_in[1];
    const float* Wk     = (const float*)d_in[2];
    const float* Wv     = (const float*)d_in[3];
    const float* Wo     = (const float*)d_in[4];
    const float* gamma  = (const float*)d_in[5];
    const float* beta   = (const float*)d_in[6];
    const float* coeffs = (const float*)d_in[7];
    float* out = (float*)d_out;

    char* ws = (char*)d_ws;
    size_t off = 0;
    auto alloc = [&](size_t bytes) -> void* {
        void* p = ws + off;
        off += (bytes + 255) & ~(size_t)255;
        return p;
    };
    ushort_t* xb    = (ushort_t*)alloc((size_t)B_ * N_ * D_ * 2);
    ushort_t* WqkvT = (ushort_t*)alloc((size_t)3 * INNER_ * D_ * 2);
    ushort_t* WoT   = (ushort_t*)alloc((size_t)D_ * INNER_ * 2);
    ushort_t* Qb    = (ushort_t*)alloc((size_t)NBH * N_ * DH_ * 2);
    ushort_t* Kb    = (ushort_t*)alloc((size_t)NBH * N_ * DH_ * 2);
    unsigned char* t0T = (unsigned char*)alloc((size_t)NBH * DH_ * N_);
    unsigned char* t1T = (unsigned char*)alloc((size_t)NBH * DH_ * N_);
    float*    y     = (float*)alloc((size_t)NBH * N_ * DH_ * 4);

    const int prep_total = B_ * N_ * D_ + 3 * INNER_ * D_ + D_ * INNER_;
    prep_kernel<<<(prep_total + 255) / 256, 256, 0, stream>>>(
        x, Wq, Wk, Wv, Wo, xb, WqkvT, WoT);
    proj_gemm<<<768, 256, 0, stream>>>(xb, WqkvT, gamma, beta, coeffs,
                                       Qb, Kb, t0T, y);

    poly_pass<<<NBH * 32, 512, 0, stream>>>(Qb, Kb, t0T, y, t1T, coeffs, 1, 1);
    poly_pass<<<NBH * 32, 512, 0, stream>>>(Qb, Kb, t1T, y, t0T, coeffs, 2, 1);
    poly_pass<<<NBH * 32, 512, 0, stream>>>(Qb, Kb, t0T, y, t1T, coeffs, 3, 0);

    out_gemm<<<512, 256, 0, stream>>>(y, WoT, out);
}